// Round 16
// baseline (976.435 us; speedup 1.0000x reference)
//
#include <hip/hip_runtime.h>
#include <stdint.h>
#include <math.h>

typedef __attribute__((ext_vector_type(8))) short short8;
typedef __attribute__((ext_vector_type(4))) short short4v;
typedef __attribute__((ext_vector_type(4))) float f32x4;

__device__ __forceinline__ short f2bf(float f){
  union { float f; uint32_t u; } x; x.f = f;
  uint32_t r = x.u + 0x7fffu + ((x.u >> 16) & 1u);
  return (short)(r >> 16);
}
__device__ __forceinline__ float bf2f(short s){
  union { uint32_t u; float f; } x; x.u = ((uint32_t)(uint16_t)s) << 16;
  return x.f;
}

__device__ __forceinline__ unsigned ld_llc_u32(const void* p){
  return __hip_atomic_load((const unsigned*)p, __ATOMIC_RELAXED, __HIP_MEMORY_SCOPE_AGENT);
}
__device__ __forceinline__ void st_llc_u32(void* p, unsigned v){
  __hip_atomic_store((unsigned*)p, v, __ATOMIC_RELAXED, __HIP_MEMORY_SCOPE_AGENT);
}

// ---------------- prep kernels ----------------

__global__ __launch_bounds__(256) void k_wt(const float* __restrict__ Wx,
                                            const float* __restrict__ Wh,
                                            const float* __restrict__ Wattn,
                                            short* __restrict__ W3T){
  __shared__ float tile[64][65];
  int bk = blockIdx.x % 48, bj = blockIdx.x / 48;
  int tx = threadIdx.x & 63, ty = threadIdx.x >> 6;
  int k0 = bk * 64, j0 = bj * 64;
  #pragma unroll
  for (int i = 0; i < 16; ++i){
    int kk = ty * 16 + i;
    int k = k0 + kk;
    const float* src = (k < 1024) ? (Wx + (size_t)k * 4096)
                     : (k < 2048) ? (Wh + (size_t)(k - 1024) * 4096)
                                  : (Wattn + (size_t)(k - 2048) * 4096);
    tile[kk][tx] = src[j0 + tx];
  }
  __syncthreads();
  #pragma unroll
  for (int i = 0; i < 16; ++i){
    int jj = ty * 16 + i;
    W3T[(size_t)(j0 + jj) * 3072 + k0 + tx] = f2bf(tile[tx][jj]);
  }
}

__global__ __launch_bounds__(256) void k_cast(const float* __restrict__ in,
                                              short* __restrict__ out, int n4){
  int i = blockIdx.x * 256 + threadIdx.x;
  if (i >= n4) return;
  float4 v = ((const float4*)in)[i];
  short4v o; o[0] = f2bf(v.x); o[1] = f2bf(v.y); o[2] = f2bf(v.z); o[3] = f2bf(v.w);
  *(short4v*)(out + (size_t)i * 4) = o;
}

__global__ __launch_bounds__(256) void k_castA(const float* __restrict__ A,
                                               short* __restrict__ Abf,
                                               short* __restrict__ Atr){
  const int n = blockIdx.x;
  const int tid = threadIdx.x;
  __shared__ short tile[256][17];
  for (int it = 0; it < 4; ++it){
    int h = it * 256 + tid;
    const float* src = A + ((size_t)n * 1024 + h) * 16;
    short o[16];
    #pragma unroll
    for (int l = 0; l < 16; ++l) o[l] = f2bf(src[l]);
    short8 p0, p1;
    #pragma unroll
    for (int l = 0; l < 8; ++l){ p0[l] = o[l]; p1[l] = o[8 + l]; }
    short8* dst = (short8*)(Abf + ((size_t)n * 1024 + h) * 16);
    dst[0] = p0; dst[1] = p1;
    #pragma unroll
    for (int l = 0; l < 16; ++l) tile[tid][l] = o[l];
    __syncthreads();
    {
      int l = tid >> 4, hc = (tid & 15) * 16;
      short tmp[16];
      #pragma unroll
      for (int k = 0; k < 16; ++k) tmp[k] = tile[hc + k][l];
      short8 q0, q1;
      #pragma unroll
      for (int k = 0; k < 8; ++k){ q0[k] = tmp[k]; q1[k] = tmp[8 + k]; }
      short8* d2 = (short8*)(Atr + (size_t)n * 16384 + l * 1024 + it * 256 + hc);
      d2[0] = q0; d2[1] = q1;
    }
    __syncthreads();
  }
}

__global__ __launch_bounds__(256) void k_init(const float* __restrict__ A,
                                              float* __restrict__ c,
                                              short* __restrict__ hb0,
                                              unsigned* __restrict__ flags){
  int idx = blockIdx.x * 256 + threadIdx.x;
  if (idx < 8192) flags[idx] = 0u;
  const float* p = A + (size_t)idx * 16;
  float s = 0.f;
  #pragma unroll
  for (int l = 0; l < 16; ++l) s += p[l];
  s *= (1.f / 16.f);
  c[idx] = s;
  hb0[idx] = f2bf(s);
}

typedef const __attribute__((address_space(1))) uint32_t* gas1_t;
typedef __attribute__((address_space(3))) uint32_t* las3_t;

// xwx repacked: [t][slot=mh*128+jb][n_loc][g][uu]  (4 KB contiguous per (t, block))
__global__ __launch_bounds__(256) void k_xwx(const short* __restrict__ xbf,
                                             const short* __restrict__ W3T,
                                             short* __restrict__ xwx){
  __shared__ short ldsA[128 * 64];
  __shared__ short ldsB[128 * 64];
  const int tid  = threadIdx.x;
  const int lane = tid & 63;
  const int wave = tid >> 6;
  const int orig = blockIdx.x;
  const int wg = (orig & 7) * 256 + (orig >> 3);
  const int n_t = wg >> 6;
  const int m_t = wg & 63;
  const int m0 = m_t * 128;
  const int n0 = n_t * 128;
  const int ra = lane & 15;
  const int q  = lane >> 4;

  f32x4 acc[4][4];
  #pragma unroll
  for (int mf = 0; mf < 4; ++mf)
    #pragma unroll
    for (int jf = 0; jf < 4; ++jf) acc[mf][jf] = f32x4{0.f,0.f,0.f,0.f};

  const int wm = wave >> 1;
  const int wn = wave & 1;

  for (int kt = 0; kt < 16; ++kt){
    const int kb = kt * 64;
    #pragma unroll
    for (int r = 0; r < 4; ++r){
      int id = (wave * 4 + r) * 64 + lane;
      int row = id >> 3, c = id & 7;
      int csrc = c ^ (row & 7);
      const short* src = xbf + (size_t)(m0 + row) * 1024 + kb + csrc * 8;
      short* dst = ldsA + (wave * 4 + r) * 512;
      __builtin_amdgcn_global_load_lds((gas1_t)(const void*)src, (las3_t)(void*)dst, 16, 0, 0);
    }
    #pragma unroll
    for (int r = 0; r < 4; ++r){
      int id = (wave * 4 + r) * 64 + lane;
      int row = id >> 3, c = id & 7;
      int csrc = c ^ (row & 7);
      const short* src = W3T + (size_t)(n0 + row) * 3072 + kb + csrc * 8;
      short* dst = ldsB + (wave * 4 + r) * 512;
      __builtin_amdgcn_global_load_lds((gas1_t)(const void*)src, (las3_t)(void*)dst, 16, 0, 0);
    }
    asm volatile("s_waitcnt vmcnt(0)" ::: "memory");
    __syncthreads();

    #pragma unroll
    for (int kk = 0; kk < 64; kk += 32){
      const int cc = (kk >> 3) + q;
      short8 af[4], bfr[4];
      #pragma unroll
      for (int mf = 0; mf < 4; ++mf){
        int row = wm * 64 + mf * 16 + ra;
        af[mf] = *(const short8*)(ldsA + row * 64 + ((cc ^ (row & 7)) << 3));
      }
      #pragma unroll
      for (int jf = 0; jf < 4; ++jf){
        int row = wn * 64 + jf * 16 + ra;
        bfr[jf] = *(const short8*)(ldsB + row * 64 + ((cc ^ (row & 7)) << 3));
      }
      #pragma unroll
      for (int mf = 0; mf < 4; ++mf)
        #pragma unroll
        for (int jf = 0; jf < 4; ++jf)
          acc[mf][jf] = __builtin_amdgcn_mfma_f32_16x16x32_bf16(af[mf], bfr[jf], acc[mf][jf], 0, 0, 0);
    }
    __syncthreads();
  }

  #pragma unroll
  for (int mf = 0; mf < 4; ++mf)
    #pragma unroll
    for (int jf = 0; jf < 4; ++jf)
      #pragma unroll
      for (int i = 0; i < 4; ++i){
        int row = m0 + wm * 64 + mf * 16 + q * 4 + i;   // row = n*64 + t
        int col = n0 + wn * 64 + jf * 16 + ra;          // col = g*1024 + cu
        int n = row >> 6, t = row & 63;
        int g = col >> 10, cu = col & 1023;
        int slot = ((n >> 6) & 1) * 128 + (cu >> 3);
        size_t addr = ((size_t)(t * 256 + slot)) * 2048 + (n & 63) * 32 + g * 8 + (cu & 7);
        xwx[addr] = f2bf(acc[mf][jf][i]);
      }
}

__global__ __launch_bounds__(256) void k_pw(const short* __restrict__ W3T,
                                            const short* __restrict__ Atr,
                                            short* __restrict__ P){
  const int tid  = threadIdx.x;
  const int lane = tid & 63;
  const int wave = tid >> 6;
  const int blk  = blockIdx.x;
  const int n    = blk >> 4;
  const int jblk = blk & 15;
  const int j0   = jblk * 256 + wave * 64;
  const int ra = lane & 15;
  const int q  = lane >> 4;

  f32x4 acc[4];
  #pragma unroll
  for (int mf = 0; mf < 4; ++mf) acc[mf] = f32x4{0.f,0.f,0.f,0.f};

  auto loadA = [&](int ks, int mf) -> short8 {
    return *(const short8*)(W3T + (size_t)(j0 + mf*16 + ra) * 3072 + 2048 + ks * 32 + q * 8);
  };
  auto loadB = [&](int ks) -> short8 {
    return *(const short8*)(Atr + (size_t)n * 16384 + ra * 1024 + ks * 32 + q * 8);
  };

  short8 aC[4], bC, aN[4], bN;
  #pragma unroll
  for (int mf = 0; mf < 4; ++mf) aC[mf] = loadA(0, mf);
  bC = loadB(0);
  for (int ks = 0; ks < 32; ++ks){
    bool more = (ks + 1) < 32;
    if (more){
      #pragma unroll
      for (int mf = 0; mf < 4; ++mf) aN[mf] = loadA(ks + 1, mf);
      bN = loadB(ks + 1);
    }
    #pragma unroll
    for (int mf = 0; mf < 4; ++mf)
      acc[mf] = __builtin_amdgcn_mfma_f32_16x16x32_bf16(aC[mf], bC, acc[mf], 0, 0, 0);
    if (more){
      #pragma unroll
      for (int mf = 0; mf < 4; ++mf) aC[mf] = aN[mf];
      bC = bN;
    }
  }
  #pragma unroll
  for (int mf = 0; mf < 4; ++mf)
    #pragma unroll
    for (int i = 0; i < 4; ++i){
      int j = j0 + mf * 16 + q * 4 + i;
      P[(size_t)(n * 4096 + j) * 16 + ra] = f2bf(acc[mf][i]);
    }
}

// ---------------- persistent recurrence kernel ----------------
// R15 base + (a) fin in disjoint LDS region (one sync removed), (b) per-wave
// atomic arrival (sync8 removed; flag counter reaches 8t), (c) contiguous xwx.
__global__ __launch_bounds__(512, 1) void k_loop(
    const short* __restrict__ W3T,
    const short* __restrict__ Abf,     // [128][1024][16] bf16
    const short* __restrict__ P,       // [128][4096][16] bf16
    short* __restrict__ hbuf,          // [65][128][1024] bf16 (rotating)
    float* __restrict__ wbuf,          // [64][128][32] f32 (rotating)
    const float* __restrict__ cbuf,    // [128][1024] f32
    const short* __restrict__ xwx,     // [64][256][2048] bf16 (repacked)
    const float* __restrict__ bias,    // [4096] f32
    float* __restrict__ out,           // [128][64][1024] f32
    unsigned* __restrict__ flags)
{
  __shared__ short Wl[32768];          // 64 KB Wh slice, XOR-swizzled
  __shared__ float redu[4608];         // [0,2048): pair-reduce; [2048,4608): padded fin
  __shared__ float sred[4][16];
  __shared__ float wlds[64][16];

  unsigned* flagsB = flags;
  unsigned* wtag   = flags + 4096;

  const int tid  = threadIdx.x;
  const int lane = tid & 63;
  const int wave = tid >> 6;
  const int bid  = blockIdx.x;
  const int mh   = bid & 1;
  const int jb   = bid >> 1;
  const int u0   = jb * 8;
  const int ra   = lane & 15;
  const int q    = lane >> 4;
  const int mf2  = wave & 1;
  const int kh   = wave >> 1;
  const bool isScore = (bid < 128);
  const int n_s  = mh * 64 + jb;
  const bool doScore = (wave < 4) && isScore;
  const int slot = mh * 128 + jb;

  // ---- prologue: Wh slice -> LDS (once)
  #pragma unroll
  for (int it = 0; it < 8; ++it){
    int c16 = it * 512 + tid;
    int jl = c16 >> 7;
    int kc = c16 & 127;
    int jf = jl >> 4, rr = jl & 15;
    int j = (jf * 2 + (rr >> 3)) * 1024 + u0 + (rr & 7);
    short8 v = *(const short8*)(W3T + (size_t)j * 3072 + 1024 + kc * 8);
    int pc = (jf * 16 + rr) * 128 + (kc ^ (rr & 7));
    *(short8*)(Wl + pc * 8) = v;
  }

  // ---- per-thread LSTM cell; hoisted step-invariant P fragments
  const int n_loc = tid >> 3, uu = tid & 7;
  const int cn = mh * 64 + n_loc;
  const int cu = u0 + uu;
  float creg = cbuf[(size_t)cn * 1024 + cu];
  const float b0 = bias[cu], b1 = bias[1024 + cu], b2 = bias[2048 + cu], b3 = bias[3072 + cu];
  short8 pA[4], pB[4];
  #pragma unroll
  for (int g = 0; g < 4; ++g){
    const short8* pp = (const short8*)(P + ((size_t)cn * 4096 + g * 1024 + cu) * 16);
    pA[g] = pp[0]; pB[g] = pp[1];
  }
  const int hh0 = tid * 4;             // score-wave h offset (tid<256)
  __syncthreads();

  for (int t = 0; t < 64; ++t){
    const short* hRp = hbuf + (size_t)t * 131072;
    short*       hWp = hbuf + (size_t)(t + 1) * 131072;
    float*       wT  = wbuf + (size_t)t * 4096;

    // ---------- xwx loads (contiguous 4 KB per block; issue before the poll) ----------
    const short* xp = xwx + ((size_t)(t * 256 + slot)) * 2048 + n_loc * 32 + uu;
    const short xw0 = xp[0], xw1 = xp[8], xw2 = xp[16], xw3 = xp[24];

    // ---------- h(t) wait: wave 0 polls counter >= 8t, barrier releases ----------
    if (t > 0){
      if (wave == 0){
        const unsigned tgt = (unsigned)(8 * t);
        for (;;){
          unsigned v0 = ld_llc_u32(&flagsB[(mh * 128 + lane * 2)     * 16]);
          unsigned v1 = ld_llc_u32(&flagsB[(mh * 128 + lane * 2 + 1) * 16]);
          unsigned mn = v0 < v1 ? v0 : v1;
          if (__all(mn >= tgt)) break;
          __builtin_amdgcn_s_sleep(2);
        }
      }
      __syncthreads();                 // release: h(t) visible
    }

    auto loadA = [&](int ks, int m) -> short8 {
      const int kk = kh * 256 + ks * 32 + q * 8;
      const int row = mh * 64 + mf2 * 32 + m * 16 + ra;
      return *(const short8*)(hRp + row * 1024 + kk);
    };
    auto loadB = [&](int ks, int jf) -> short8 {
      const int kcg = kh * 32 + ks * 4 + q;
      const int sw = kcg ^ (ra & 7);
      return *(const short8*)(Wl + (((jf * 16 + ra) * 128) + sw) * 8);
    };

    // ---------- non-score waves: early A prefetch ----------
    short8 Ab[4][2];
    if (!doScore){
      #pragma unroll
      for (int p = 0; p < 4; ++p){ Ab[p][0] = loadA(p, 0); Ab[p][1] = loadA(p, 1); }
    }

    // ---------- scores (score blocks, waves 0-3) ----------
    if (doScore){
      short8 af0[4], af1[4];
      #pragma unroll
      for (int j = 0; j < 4; ++j){
        const short8* ap = (const short8*)(Abf + ((size_t)n_s * 1024 + hh0 + j) * 16);
        af0[j] = ap[0]; af1[j] = ap[1];
      }
      uint64_t hq = *(const uint64_t*)(hRp + n_s * 1024 + hh0);
      float hv[4];
      #pragma unroll
      for (int j = 0; j < 4; ++j) hv[j] = bf2f((short)((hq >> (16 * j)) & 0xffffu));
      float sc[16];
      #pragma unroll
      for (int l = 0; l < 8; ++l){
        float s0 = 0.f, s1 = 0.f;
        #pragma unroll
        for (int j = 0; j < 4; ++j){ s0 += hv[j] * bf2f(af0[j][l]); s1 += hv[j] * bf2f(af1[j][l]); }
        sc[l] = s0; sc[8 + l] = s1;
      }
      #pragma unroll
      for (int off = 1; off < 64; off <<= 1)
        #pragma unroll
        for (int l = 0; l < 16; ++l) sc[l] += __shfl_xor(sc[l], off);
      if (lane == 0)
        #pragma unroll
        for (int l = 0; l < 16; ++l) sred[wave][l] = sc[l];
    }
    __syncthreads();                   // sync1: sred ready

    // ---------- wave 0 of score blocks: softmax -> publish w + tag ----------
    if (wave == 0 && isScore){
      float s[16], mx = -1e30f, sum = 0.f;
      #pragma unroll
      for (int l = 0; l < 16; ++l){
        s[l] = (sred[0][l] + sred[1][l] + sred[2][l] + sred[3][l]) * 0.03125f;
        mx = fmaxf(mx, s[l]);
      }
      #pragma unroll
      for (int l = 0; l < 16; ++l){ s[l] = __expf(s[l] - mx); sum += s[l]; }
      const float inv = 1.f / sum;
      #pragma unroll
      for (int l = 0; l < 16; ++l){
        if (lane == l){
          union { float f; unsigned u; } cv; cv.f = s[l] * inv;
          st_llc_u32(&wT[n_s * 32 + l], cv.u);
        }
      }
      asm volatile("s_waitcnt vmcnt(0)" ::: "memory");
      if (lane == 0) st_llc_u32(&wtag[n_s * 16], (unsigned)(t + 1));
    }

    // ---------- GEMM h@Wh ----------
    if (doScore){
      #pragma unroll
      for (int p = 0; p < 4; ++p){ Ab[p][0] = loadA(p, 0); Ab[p][1] = loadA(p, 1); }
    }
    short8 Bb[2][2];
    Bb[0][0] = loadB(0, 0); Bb[0][1] = loadB(0, 1);
    Bb[1][0] = loadB(1, 0); Bb[1][1] = loadB(1, 1);

    f32x4 acc[2][2];
    acc[0][0] = f32x4{0.f,0.f,0.f,0.f}; acc[0][1] = f32x4{0.f,0.f,0.f,0.f};
    acc[1][0] = f32x4{0.f,0.f,0.f,0.f}; acc[1][1] = f32x4{0.f,0.f,0.f,0.f};

    #pragma unroll
    for (int ks = 0; ks < 8; ++ks){
      short8 av0 = Ab[ks & 3][0], av1 = Ab[ks & 3][1];
      short8 bv0 = Bb[ks & 1][0], bv1 = Bb[ks & 1][1];
      if (ks < 4){ Ab[ks & 3][0] = loadA(ks + 4, 0); Ab[ks & 3][1] = loadA(ks + 4, 1); }
      if (ks < 6){ Bb[ks & 1][0] = loadB(ks + 2, 0); Bb[ks & 1][1] = loadB(ks + 2, 1); }
      acc[0][0] = __builtin_amdgcn_mfma_f32_16x16x32_bf16(av0, bv0, acc[0][0], 0, 0, 0);
      acc[0][1] = __builtin_amdgcn_mfma_f32_16x16x32_bf16(av0, bv1, acc[0][1], 0, 0, 0);
      acc[1][0] = __builtin_amdgcn_mfma_f32_16x16x32_bf16(av1, bv0, acc[1][0], 0, 0, 0);
      acc[1][1] = __builtin_amdgcn_mfma_f32_16x16x32_bf16(av1, bv1, acc[1][1], 0, 0, 0);
    }

    // ---------- reduction over kh (pairs) ----------
    auto ridx = [&](int m2, int khq, int m, int jf) -> float* {
      return &redu[((((m2 * 2 + khq) * 2 + m) * 2 + jf) * 64 + lane) * 4];
    };
    if (kh & 1){
      *(f32x4*)ridx(mf2, kh >> 1, 0, 0) = acc[0][0];
      *(f32x4*)ridx(mf2, kh >> 1, 0, 1) = acc[0][1];
      *(f32x4*)ridx(mf2, kh >> 1, 1, 0) = acc[1][0];
      *(f32x4*)ridx(mf2, kh >> 1, 1, 1) = acc[1][1];
    }
    __syncthreads();                   // sync3
    if (!(kh & 1)){
      acc[0][0] += *(const f32x4*)ridx(mf2, kh >> 1, 0, 0);
      acc[0][1] += *(const f32x4*)ridx(mf2, kh >> 1, 0, 1);
      acc[1][0] += *(const f32x4*)ridx(mf2, kh >> 1, 1, 0);
      acc[1][1] += *(const f32x4*)ridx(mf2, kh >> 1, 1, 1);
    }
    if (wave == 2){
      const unsigned tgt = (unsigned)(t + 1);
      for (;;){
        unsigned v = ld_llc_u32(&wtag[(mh * 64 + lane) * 16]);
        if (__all(v >= tgt)) break;
        __builtin_amdgcn_s_sleep(2);
      }
      const f32x4* wp = (const f32x4*)(wT + (mh * 64 + lane) * 32);
      f32x4 w0 = wp[0], w1 = wp[1], w2 = wp[2], w3 = wp[3];
      f32x4* wd = (f32x4*)&wlds[lane][0];
      wd[0] = w0; wd[1] = w1; wd[2] = w2; wd[3] = w3;
    }
    __syncthreads();                   // sync4
    if (kh == 2){
      *(f32x4*)ridx(mf2, 0, 0, 0) = acc[0][0];
      *(f32x4*)ridx(mf2, 0, 0, 1) = acc[0][1];
      *(f32x4*)ridx(mf2, 0, 1, 0) = acc[1][0];
      *(f32x4*)ridx(mf2, 0, 1, 1) = acc[1][1];
    }
    __syncthreads();                   // sync5
    if (kh == 0){
      acc[0][0] += *(const f32x4*)ridx(mf2, 0, 0, 0);
      acc[0][1] += *(const f32x4*)ridx(mf2, 0, 0, 1);
      acc[1][0] += *(const f32x4*)ridx(mf2, 0, 1, 0);
      acc[1][1] += *(const f32x4*)ridx(mf2, 0, 1, 1);
      // fin write (disjoint region [2048,4608): no barrier needed after the add)
      #pragma unroll
      for (int m = 0; m < 2; ++m)
        #pragma unroll
        for (int jf = 0; jf < 2; ++jf){
          const int g = jf * 2 + (ra >> 3);
          const int nl = mf2 * 32 + m * 16 + q * 4;
          #pragma unroll
          for (int i = 0; i < 4; ++i)
            redu[2048 + g * 640 + (nl + i) * 10 + (ra & 7)] = acc[m][jf][i];
        }
    }
    __syncthreads();                   // sync7: fin + wlds ready

    // ---------- epilogue: 1 thread per (n,u) cell ----------
    float hn;
    {
      float wl[16];
      #pragma unroll
      for (int l = 0; l < 16; ++l) wl[l] = wlds[n_loc][l];
      float pg[4];
      #pragma unroll
      for (int g = 0; g < 4; ++g){
        float s = 0.f;
        #pragma unroll
        for (int l = 0; l < 8; ++l){ s += bf2f(pA[g][l]) * wl[l]; s += bf2f(pB[g][l]) * wl[8 + l]; }
        pg[g] = s;
      }
      const int fb = n_loc * 10 + uu;
      const float av = redu[2048 + fb]        + bf2f(xw0) + pg[0] + b0;
      const float fv = redu[2048 + 640 + fb]  + bf2f(xw1) + pg[1] + b1;
      const float ov = redu[2048 + 1280 + fb] + bf2f(xw2) + pg[2] + b2;
      const float gv = redu[2048 + 1920 + fb] + bf2f(xw3) + pg[3] + b3;
      const float ig = 1.f / (1.f + __expf(-av));
      const float fg = 1.f / (1.f + __expf(-fv));
      const float og = 1.f / (1.f + __expf(-ov));
      const float gcl = fminf(fmaxf(gv, -20.f), 20.f);
      const float e2g = __expf(2.f * gcl);
      const float gg = (e2g - 1.f) / (e2g + 1.f);
      creg = fg * creg + ig * gg;
      const float ccl = fminf(fmaxf(creg, -20.f), 20.f);
      const float e2c = __expf(2.f * ccl);
      const float th = (e2c - 1.f) / (e2c + 1.f);
      hn = og * th;
      const float hn2 = __shfl_xor(hn, 1);
      if ((tid & 1) == 0){
        unsigned pk = (unsigned)(unsigned short)f2bf(hn)
                    | ((unsigned)(unsigned short)f2bf(hn2) << 16);
        st_llc_u32(hWp + (size_t)cn * 1024 + cu, pk);
      }
    }
    // per-wave arrival: drain own h stores, then +1 on the block counter
    if (t < 63){
      asm volatile("s_waitcnt vmcnt(0)" ::: "memory");
      if (lane == 0)
        __hip_atomic_fetch_add(&flagsB[(mh * 128 + jb) * 16], 1u,
                               __ATOMIC_RELAXED, __HIP_MEMORY_SCOPE_AGENT);
    }
    __builtin_nontemporal_store(hn, &out[((size_t)cn * 64 + t) * 1024 + cu]);
  }
}

// ---------------- launch ----------------

extern "C" void kernel_launch(void* const* d_in, const int* in_sizes, int n_in,
                              void* d_out, int out_size, void* d_ws, size_t ws_size,
                              hipStream_t stream)
{
  const float* x     = (const float*)d_in[0];
  const float* A     = (const float*)d_in[1];
  const float* Wx    = (const float*)d_in[2];
  const float* Wh    = (const float*)d_in[3];
  const float* Wattn = (const float*)d_in[4];
  const float* b     = (const float*)d_in[5];
  float* out = (float*)d_out;
  char* ws = (char*)d_ws;

  short*    W3T   = (short*)(ws + 0);             // 25165824
  short*    Abf   = (short*)(ws + 25165824);      //  4194304
  short*    Atr   = (short*)(ws + 29360128);      //  4194304
  short*    xbf   = (short*)(ws + 33554432);      // 16777216
  short*    xwx   = (short*)(ws + 50331648);      // 67108864
  short*    P     = (short*)(ws + 117440512);     // 16777216
  short*    hbuf  = (short*)(ws + 134217728);     // 17039360
  float*    wbuf  = (float*)(ws + 151257088);     //  1048576
  float*    cbuf  = (float*)(ws + 152305664);     //   524288
  unsigned* flags = (unsigned*)(ws + 152829952);  //    32768

  hipLaunchKernelGGL(k_wt,    dim3(48 * 64), dim3(256), 0, stream, Wx, Wh, Wattn, W3T);
  hipLaunchKernelGGL(k_cast,  dim3(2097152 / 256), dim3(256), 0, stream, x, xbf, 2097152);
  hipLaunchKernelGGL(k_castA, dim3(128), dim3(256), 0, stream, A, Abf, Atr);
  hipLaunchKernelGGL(k_init,  dim3(512), dim3(256), 0, stream, A, cbuf, hbuf, flags);
  hipLaunchKernelGGL(k_xwx,   dim3(2048), dim3(256), 0, stream, xbf, W3T, xwx);
  hipLaunchKernelGGL(k_pw,    dim3(2048), dim3(256), 0, stream, W3T, Atr, P);
  hipLaunchKernelGGL(k_loop,  dim3(256), dim3(512), 0, stream,
                     W3T, Abf, P, hbuf, wbuf, cbuf, xwx, b, out, flags);
}

// Round 17
// 799.360 us; speedup vs baseline: 1.2215x; 1.2215x over previous
//
#include <hip/hip_runtime.h>
#include <stdint.h>
#include <math.h>

typedef __attribute__((ext_vector_type(8))) short short8;
typedef __attribute__((ext_vector_type(4))) short short4v;
typedef __attribute__((ext_vector_type(4))) float f32x4;

__device__ __forceinline__ short f2bf(float f){
  union { float f; uint32_t u; } x; x.f = f;
  uint32_t r = x.u + 0x7fffu + ((x.u >> 16) & 1u);
  return (short)(r >> 16);
}
__device__ __forceinline__ float bf2f(short s){
  union { uint32_t u; float f; } x; x.u = ((uint32_t)(uint16_t)s) << 16;
  return x.f;
}

__device__ __forceinline__ unsigned ld_llc_u32(const void* p){
  return __hip_atomic_load((const unsigned*)p, __ATOMIC_RELAXED, __HIP_MEMORY_SCOPE_AGENT);
}
__device__ __forceinline__ void st_llc_u32(void* p, unsigned v){
  __hip_atomic_store((unsigned*)p, v, __ATOMIC_RELAXED, __HIP_MEMORY_SCOPE_AGENT);
}

// ---------------- prep kernels ----------------

__global__ __launch_bounds__(256) void k_wt(const float* __restrict__ Wx,
                                            const float* __restrict__ Wh,
                                            const float* __restrict__ Wattn,
                                            short* __restrict__ W3T){
  __shared__ float tile[64][65];
  int bk = blockIdx.x % 48, bj = blockIdx.x / 48;
  int tx = threadIdx.x & 63, ty = threadIdx.x >> 6;
  int k0 = bk * 64, j0 = bj * 64;
  #pragma unroll
  for (int i = 0; i < 16; ++i){
    int kk = ty * 16 + i;
    int k = k0 + kk;
    const float* src = (k < 1024) ? (Wx + (size_t)k * 4096)
                     : (k < 2048) ? (Wh + (size_t)(k - 1024) * 4096)
                                  : (Wattn + (size_t)(k - 2048) * 4096);
    tile[kk][tx] = src[j0 + tx];
  }
  __syncthreads();
  #pragma unroll
  for (int i = 0; i < 16; ++i){
    int jj = ty * 16 + i;
    W3T[(size_t)(j0 + jj) * 3072 + k0 + tx] = f2bf(tile[tx][jj]);
  }
}

__global__ __launch_bounds__(256) void k_cast(const float* __restrict__ in,
                                              short* __restrict__ out, int n4){
  int i = blockIdx.x * 256 + threadIdx.x;
  if (i >= n4) return;
  float4 v = ((const float4*)in)[i];
  short4v o; o[0] = f2bf(v.x); o[1] = f2bf(v.y); o[2] = f2bf(v.z); o[3] = f2bf(v.w);
  *(short4v*)(out + (size_t)i * 4) = o;
}

__global__ __launch_bounds__(256) void k_castA(const float* __restrict__ A,
                                               short* __restrict__ Abf,
                                               short* __restrict__ Atr){
  const int n = blockIdx.x;
  const int tid = threadIdx.x;
  __shared__ short tile[256][17];
  for (int it = 0; it < 4; ++it){
    int h = it * 256 + tid;
    const float* src = A + ((size_t)n * 1024 + h) * 16;
    short o[16];
    #pragma unroll
    for (int l = 0; l < 16; ++l) o[l] = f2bf(src[l]);
    short8 p0, p1;
    #pragma unroll
    for (int l = 0; l < 8; ++l){ p0[l] = o[l]; p1[l] = o[8 + l]; }
    short8* dst = (short8*)(Abf + ((size_t)n * 1024 + h) * 16);
    dst[0] = p0; dst[1] = p1;
    #pragma unroll
    for (int l = 0; l < 16; ++l) tile[tid][l] = o[l];
    __syncthreads();
    {
      int l = tid >> 4, hc = (tid & 15) * 16;
      short tmp[16];
      #pragma unroll
      for (int k = 0; k < 16; ++k) tmp[k] = tile[hc + k][l];
      short8 q0, q1;
      #pragma unroll
      for (int k = 0; k < 8; ++k){ q0[k] = tmp[k]; q1[k] = tmp[8 + k]; }
      short8* d2 = (short8*)(Atr + (size_t)n * 16384 + l * 1024 + it * 256 + hc);
      d2[0] = q0; d2[1] = q1;
    }
    __syncthreads();
  }
}

__global__ __launch_bounds__(256) void k_init(const float* __restrict__ A,
                                              float* __restrict__ c,
                                              short* __restrict__ hb0,
                                              unsigned* __restrict__ flags){
  int idx = blockIdx.x * 256 + threadIdx.x;
  if (idx < 8192) flags[idx] = 0u;
  const float* p = A + (size_t)idx * 16;
  float s = 0.f;
  #pragma unroll
  for (int l = 0; l < 16; ++l) s += p[l];
  s *= (1.f / 16.f);
  c[idx] = s;
  hb0[idx] = f2bf(s);
}

typedef const __attribute__((address_space(1))) uint32_t* gas1_t;
typedef __attribute__((address_space(3))) uint32_t* las3_t;

__global__ __launch_bounds__(256) void k_xwx(const short* __restrict__ xbf,
                                             const short* __restrict__ W3T,
                                             short* __restrict__ xwx){
  __shared__ short ldsA[128 * 64];
  __shared__ short ldsB[128 * 64];
  const int tid  = threadIdx.x;
  const int lane = tid & 63;
  const int wave = tid >> 6;
  const int orig = blockIdx.x;
  const int wg = (orig & 7) * 256 + (orig >> 3);
  const int n_t = wg >> 6;
  const int m_t = wg & 63;
  const int m0 = m_t * 128;
  const int n0 = n_t * 128;
  const int ra = lane & 15;
  const int q  = lane >> 4;

  f32x4 acc[4][4];
  #pragma unroll
  for (int mf = 0; mf < 4; ++mf)
    #pragma unroll
    for (int jf = 0; jf < 4; ++jf) acc[mf][jf] = f32x4{0.f,0.f,0.f,0.f};

  const int wm = wave >> 1;
  const int wn = wave & 1;

  for (int kt = 0; kt < 16; ++kt){
    const int kb = kt * 64;
    #pragma unroll
    for (int r = 0; r < 4; ++r){
      int id = (wave * 4 + r) * 64 + lane;
      int row = id >> 3, c = id & 7;
      int csrc = c ^ (row & 7);
      const short* src = xbf + (size_t)(m0 + row) * 1024 + kb + csrc * 8;
      short* dst = ldsA + (wave * 4 + r) * 512;
      __builtin_amdgcn_global_load_lds((gas1_t)(const void*)src, (las3_t)(void*)dst, 16, 0, 0);
    }
    #pragma unroll
    for (int r = 0; r < 4; ++r){
      int id = (wave * 4 + r) * 64 + lane;
      int row = id >> 3, c = id & 7;
      int csrc = c ^ (row & 7);
      const short* src = W3T + (size_t)(n0 + row) * 3072 + kb + csrc * 8;
      short* dst = ldsB + (wave * 4 + r) * 512;
      __builtin_amdgcn_global_load_lds((gas1_t)(const void*)src, (las3_t)(void*)dst, 16, 0, 0);
    }
    asm volatile("s_waitcnt vmcnt(0)" ::: "memory");
    __syncthreads();

    #pragma unroll
    for (int kk = 0; kk < 64; kk += 32){
      const int cc = (kk >> 3) + q;
      short8 af[4], bfr[4];
      #pragma unroll
      for (int mf = 0; mf < 4; ++mf){
        int row = wm * 64 + mf * 16 + ra;
        af[mf] = *(const short8*)(ldsA + row * 64 + ((cc ^ (row & 7)) << 3));
      }
      #pragma unroll
      for (int jf = 0; jf < 4; ++jf){
        int row = wn * 64 + jf * 16 + ra;
        bfr[jf] = *(const short8*)(ldsB + row * 64 + ((cc ^ (row & 7)) << 3));
      }
      #pragma unroll
      for (int mf = 0; mf < 4; ++mf)
        #pragma unroll
        for (int jf = 0; jf < 4; ++jf)
          acc[mf][jf] = __builtin_amdgcn_mfma_f32_16x16x32_bf16(af[mf], bfr[jf], acc[mf][jf], 0, 0, 0);
    }
    __syncthreads();
  }

  #pragma unroll
  for (int mf = 0; mf < 4; ++mf)
    #pragma unroll
    for (int jf = 0; jf < 4; ++jf)
      #pragma unroll
      for (int i = 0; i < 4; ++i){
        int row = m0 + wm * 64 + mf * 16 + q * 4 + i;
        int col = n0 + wn * 64 + jf * 16 + ra;
        xwx[(size_t)row * 4096 + col] = f2bf(acc[mf][jf][i]);
      }
}

__global__ __launch_bounds__(256) void k_pw(const short* __restrict__ W3T,
                                            const short* __restrict__ Atr,
                                            short* __restrict__ P){
  const int tid  = threadIdx.x;
  const int lane = tid & 63;
  const int wave = tid >> 6;
  const int blk  = blockIdx.x;
  const int n    = blk >> 4;
  const int jblk = blk & 15;
  const int j0   = jblk * 256 + wave * 64;
  const int ra = lane & 15;
  const int q  = lane >> 4;

  f32x4 acc[4];
  #pragma unroll
  for (int mf = 0; mf < 4; ++mf) acc[mf] = f32x4{0.f,0.f,0.f,0.f};

  auto loadA = [&](int ks, int mf) -> short8 {
    return *(const short8*)(W3T + (size_t)(j0 + mf*16 + ra) * 3072 + 2048 + ks * 32 + q * 8);
  };
  auto loadB = [&](int ks) -> short8 {
    return *(const short8*)(Atr + (size_t)n * 16384 + ra * 1024 + ks * 32 + q * 8);
  };

  short8 aC[4], bC, aN[4], bN;
  #pragma unroll
  for (int mf = 0; mf < 4; ++mf) aC[mf] = loadA(0, mf);
  bC = loadB(0);
  for (int ks = 0; ks < 32; ++ks){
    bool more = (ks + 1) < 32;
    if (more){
      #pragma unroll
      for (int mf = 0; mf < 4; ++mf) aN[mf] = loadA(ks + 1, mf);
      bN = loadB(ks + 1);
    }
    #pragma unroll
    for (int mf = 0; mf < 4; ++mf)
      acc[mf] = __builtin_amdgcn_mfma_f32_16x16x32_bf16(aC[mf], bC, acc[mf], 0, 0, 0);
    if (more){
      #pragma unroll
      for (int mf = 0; mf < 4; ++mf) aC[mf] = aN[mf];
      bC = bN;
    }
  }
  #pragma unroll
  for (int mf = 0; mf < 4; ++mf)
    #pragma unroll
    for (int i = 0; i < 4; ++i){
      int j = j0 + mf * 16 + q * 4 + i;
      P[(size_t)(n * 4096 + j) * 16 + ra] = f2bf(acc[mf][i]);
    }
}

// ---------------- persistent recurrence kernel (R15 best-known) ----------------
__global__ __launch_bounds__(512, 1) void k_loop(
    const short* __restrict__ W3T,
    const short* __restrict__ Abf,     // [128][1024][16] bf16
    const short* __restrict__ P,       // [128][4096][16] bf16
    short* __restrict__ hbuf,          // [65][128][1024] bf16 (rotating)
    float* __restrict__ wbuf,          // [64][128][32] f32 (rotating)
    const float* __restrict__ cbuf,    // [128][1024] f32
    const short* __restrict__ xwx,     // [8192][4096] bf16
    const float* __restrict__ bias,    // [4096] f32
    float* __restrict__ out,           // [128][64][1024] f32
    unsigned* __restrict__ flags)
{
  __shared__ short Wl[32768];          // 64 KB Wh slice, XOR-swizzled
  __shared__ float redu[4096];         // pair-reduce + padded fin union
  __shared__ float sred[4][16];
  __shared__ float wlds[64][16];

  unsigned* flagsB = flags;
  unsigned* wtag   = flags + 4096;

  const int tid  = threadIdx.x;
  const int lane = tid & 63;
  const int wave = tid >> 6;
  const int bid  = blockIdx.x;
  const int mh   = bid & 1;
  const int jb   = bid >> 1;
  const int u0   = jb * 8;
  const int ra   = lane & 15;
  const int q    = lane >> 4;
  const int mf2  = wave & 1;
  const int kh   = wave >> 1;
  const bool isScore = (bid < 128);
  const int n_s  = mh * 64 + jb;
  const bool doScore = (wave < 4) && isScore;

  // ---- prologue: Wh slice -> LDS (once)
  #pragma unroll
  for (int it = 0; it < 8; ++it){
    int c16 = it * 512 + tid;
    int jl = c16 >> 7;
    int kc = c16 & 127;
    int jf = jl >> 4, rr = jl & 15;
    int j = (jf * 2 + (rr >> 3)) * 1024 + u0 + (rr & 7);
    short8 v = *(const short8*)(W3T + (size_t)j * 3072 + 1024 + kc * 8);
    int pc = (jf * 16 + rr) * 128 + (kc ^ (rr & 7));
    *(short8*)(Wl + pc * 8) = v;
  }

  // ---- per-thread LSTM cell; hoisted step-invariant P fragments (64 VGPR)
  const int n_loc = tid >> 3, uu = tid & 7;
  const int cn = mh * 64 + n_loc;
  const int cu = u0 + uu;
  float creg = cbuf[(size_t)cn * 1024 + cu];
  const float b0 = bias[cu], b1 = bias[1024 + cu], b2 = bias[2048 + cu], b3 = bias[3072 + cu];
  short8 pA[4], pB[4];
  #pragma unroll
  for (int g = 0; g < 4; ++g){
    const short8* pp = (const short8*)(P + ((size_t)cn * 4096 + g * 1024 + cu) * 16);
    pA[g] = pp[0]; pB[g] = pp[1];
  }
  const int hh0 = tid * 4;             // score-wave h offset (tid<256)
  __syncthreads();

  for (int t = 0; t < 64; ++t){
    const short* hRp = hbuf + (size_t)t * 131072;
    short*       hWp = hbuf + (size_t)(t + 1) * 131072;
    float*       wT  = wbuf + (size_t)t * 4096;

    // ---------- xwx loads (constant; issue before the poll) ----------
    const short* xp = xwx + ((size_t)cn * 64 + t) * 4096;
    const short xw0 = xp[cu], xw1 = xp[1024 + cu], xw2 = xp[2048 + cu], xw3 = xp[3072 + cu];

    // ---------- h(t) flag wait: wave 0 polls, barrier releases ----------
    if (t > 0){
      if (wave == 0){
        const unsigned tgt = (unsigned)t;
        for (;;){
          unsigned v0 = ld_llc_u32(&flagsB[(mh * 128 + lane * 2)     * 16]);
          unsigned v1 = ld_llc_u32(&flagsB[(mh * 128 + lane * 2 + 1) * 16]);
          unsigned mn = v0 < v1 ? v0 : v1;
          if (__all(mn >= tgt)) break;
          __builtin_amdgcn_s_sleep(2);
        }
      }
      __syncthreads();                 // release: h(t) visible
    }

    auto loadA = [&](int ks, int m) -> short8 {
      const int kk = kh * 256 + ks * 32 + q * 8;
      const int row = mh * 64 + mf2 * 32 + m * 16 + ra;
      return *(const short8*)(hRp + row * 1024 + kk);
    };
    auto loadB = [&](int ks, int jf) -> short8 {
      const int kcg = kh * 32 + ks * 4 + q;
      const int sw = kcg ^ (ra & 7);
      return *(const short8*)(Wl + (((jf * 16 + ra) * 128) + sw) * 8);
    };

    // ---------- non-score waves: early A prefetch (overlaps score phase) ----------
    short8 Ab[4][2];
    if (!doScore){
      #pragma unroll
      for (int p = 0; p < 4; ++p){ Ab[p][0] = loadA(p, 0); Ab[p][1] = loadA(p, 1); }
    }

    // ---------- scores (score blocks, waves 0-3; af reloaded from L2) ----------
    if (doScore){
      short8 af0[4], af1[4];
      #pragma unroll
      for (int j = 0; j < 4; ++j){
        const short8* ap = (const short8*)(Abf + ((size_t)n_s * 1024 + hh0 + j) * 16);
        af0[j] = ap[0]; af1[j] = ap[1];
      }
      uint64_t hq = *(const uint64_t*)(hRp + n_s * 1024 + hh0);
      float hv[4];
      #pragma unroll
      for (int j = 0; j < 4; ++j) hv[j] = bf2f((short)((hq >> (16 * j)) & 0xffffu));
      float sc[16];
      #pragma unroll
      for (int l = 0; l < 8; ++l){
        float s0 = 0.f, s1 = 0.f;
        #pragma unroll
        for (int j = 0; j < 4; ++j){ s0 += hv[j] * bf2f(af0[j][l]); s1 += hv[j] * bf2f(af1[j][l]); }
        sc[l] = s0; sc[8 + l] = s1;
      }
      #pragma unroll
      for (int off = 1; off < 64; off <<= 1)
        #pragma unroll
        for (int l = 0; l < 16; ++l) sc[l] += __shfl_xor(sc[l], off);
      if (lane == 0)
        #pragma unroll
        for (int l = 0; l < 16; ++l) sred[wave][l] = sc[l];
    }
    __syncthreads();                   // sync1: sred ready (prefetch drained too)

    // ---------- wave 0 of score blocks: softmax -> publish w + tag ----------
    if (wave == 0 && isScore){
      float s[16], mx = -1e30f, sum = 0.f;
      #pragma unroll
      for (int l = 0; l < 16; ++l){
        s[l] = (sred[0][l] + sred[1][l] + sred[2][l] + sred[3][l]) * 0.03125f;
        mx = fmaxf(mx, s[l]);
      }
      #pragma unroll
      for (int l = 0; l < 16; ++l){ s[l] = __expf(s[l] - mx); sum += s[l]; }
      const float inv = 1.f / sum;
      #pragma unroll
      for (int l = 0; l < 16; ++l){
        if (lane == l){
          union { float f; unsigned u; } cv; cv.f = s[l] * inv;
          st_llc_u32(&wT[n_s * 32 + l], cv.u);
        }
      }
      asm volatile("s_waitcnt vmcnt(0)" ::: "memory");
      if (lane == 0) st_llc_u32(&wtag[n_s * 16], (unsigned)(t + 1));
    }

    // ---------- GEMM h@Wh ----------
    if (doScore){
      #pragma unroll
      for (int p = 0; p < 4; ++p){ Ab[p][0] = loadA(p, 0); Ab[p][1] = loadA(p, 1); }
    }
    short8 Bb[2][2];
    Bb[0][0] = loadB(0, 0); Bb[0][1] = loadB(0, 1);
    Bb[1][0] = loadB(1, 0); Bb[1][1] = loadB(1, 1);

    f32x4 acc[2][2];
    acc[0][0] = f32x4{0.f,0.f,0.f,0.f}; acc[0][1] = f32x4{0.f,0.f,0.f,0.f};
    acc[1][0] = f32x4{0.f,0.f,0.f,0.f}; acc[1][1] = f32x4{0.f,0.f,0.f,0.f};

    #pragma unroll
    for (int ks = 0; ks < 8; ++ks){
      short8 av0 = Ab[ks & 3][0], av1 = Ab[ks & 3][1];
      short8 bv0 = Bb[ks & 1][0], bv1 = Bb[ks & 1][1];
      if (ks < 4){ Ab[ks & 3][0] = loadA(ks + 4, 0); Ab[ks & 3][1] = loadA(ks + 4, 1); }
      if (ks < 6){ Bb[ks & 1][0] = loadB(ks + 2, 0); Bb[ks & 1][1] = loadB(ks + 2, 1); }
      acc[0][0] = __builtin_amdgcn_mfma_f32_16x16x32_bf16(av0, bv0, acc[0][0], 0, 0, 0);
      acc[0][1] = __builtin_amdgcn_mfma_f32_16x16x32_bf16(av0, bv1, acc[0][1], 0, 0, 0);
      acc[1][0] = __builtin_amdgcn_mfma_f32_16x16x32_bf16(av1, bv0, acc[1][0], 0, 0, 0);
      acc[1][1] = __builtin_amdgcn_mfma_f32_16x16x32_bf16(av1, bv1, acc[1][1], 0, 0, 0);
    }

    // ---------- reduction over kh (pairs) ----------
    auto ridx = [&](int m2, int khq, int m, int jf) -> float* {
      return &redu[((((m2 * 2 + khq) * 2 + m) * 2 + jf) * 64 + lane) * 4];
    };
    if (kh & 1){
      *(f32x4*)ridx(mf2, kh >> 1, 0, 0) = acc[0][0];
      *(f32x4*)ridx(mf2, kh >> 1, 0, 1) = acc[0][1];
      *(f32x4*)ridx(mf2, kh >> 1, 1, 0) = acc[1][0];
      *(f32x4*)ridx(mf2, kh >> 1, 1, 1) = acc[1][1];
    }
    __syncthreads();                   // sync3
    if (!(kh & 1)){
      acc[0][0] += *(const f32x4*)ridx(mf2, kh >> 1, 0, 0);
      acc[0][1] += *(const f32x4*)ridx(mf2, kh >> 1, 0, 1);
      acc[1][0] += *(const f32x4*)ridx(mf2, kh >> 1, 1, 0);
      acc[1][1] += *(const f32x4*)ridx(mf2, kh >> 1, 1, 1);
    }
    if (wave == 2){
      const unsigned tgt = (unsigned)(t + 1);
      for (;;){
        unsigned v = ld_llc_u32(&wtag[(mh * 64 + lane) * 16]);
        if (__all(v >= tgt)) break;
        __builtin_amdgcn_s_sleep(2);
      }
      const f32x4* wp = (const f32x4*)(wT + (mh * 64 + lane) * 32);
      f32x4 w0 = wp[0], w1 = wp[1], w2 = wp[2], w3 = wp[3];
      f32x4* wd = (f32x4*)&wlds[lane][0];
      wd[0] = w0; wd[1] = w1; wd[2] = w2; wd[3] = w3;
    }
    __syncthreads();                   // sync4
    if (kh == 2){
      *(f32x4*)ridx(mf2, 0, 0, 0) = acc[0][0];
      *(f32x4*)ridx(mf2, 0, 0, 1) = acc[0][1];
      *(f32x4*)ridx(mf2, 0, 1, 0) = acc[1][0];
      *(f32x4*)ridx(mf2, 0, 1, 1) = acc[1][1];
    }
    __syncthreads();                   // sync5
    if (kh == 0){
      acc[0][0] += *(const f32x4*)ridx(mf2, 0, 0, 0);
      acc[0][1] += *(const f32x4*)ridx(mf2, 0, 0, 1);
      acc[1][0] += *(const f32x4*)ridx(mf2, 0, 1, 0);
      acc[1][1] += *(const f32x4*)ridx(mf2, 0, 1, 1);
    }
    __syncthreads();                   // sync6
    if (kh == 0){
      // padded fin: fin[g*640 + nl*10 + uu] -> write banks 8q+(ra&7), 2-way max
      #pragma unroll
      for (int m = 0; m < 2; ++m)
        #pragma unroll
        for (int jf = 0; jf < 2; ++jf){
          const int g = jf * 2 + (ra >> 3);
          const int nl = mf2 * 32 + m * 16 + q * 4;
          #pragma unroll
          for (int i = 0; i < 4; ++i)
            redu[g * 640 + (nl + i) * 10 + (ra & 7)] = acc[m][jf][i];
        }
    }
    __syncthreads();                   // sync7

    // ---------- epilogue: 1 thread per (n,u) cell ----------
    float hn;
    {
      float wl[16];
      #pragma unroll
      for (int l = 0; l < 16; ++l) wl[l] = wlds[n_loc][l];
      float pg[4];
      #pragma unroll
      for (int g = 0; g < 4; ++g){
        float s = 0.f;
        #pragma unroll
        for (int l = 0; l < 8; ++l){ s += bf2f(pA[g][l]) * wl[l]; s += bf2f(pB[g][l]) * wl[8 + l]; }
        pg[g] = s;
      }
      const int fb = n_loc * 10 + uu;
      const float av = redu[fb]         + bf2f(xw0) + pg[0] + b0;
      const float fv = redu[640 + fb]   + bf2f(xw1) + pg[1] + b1;
      const float ov = redu[1280 + fb]  + bf2f(xw2) + pg[2] + b2;
      const float gv = redu[1920 + fb]  + bf2f(xw3) + pg[3] + b3;
      const float ig = 1.f / (1.f + __expf(-av));
      const float fg = 1.f / (1.f + __expf(-fv));
      const float og = 1.f / (1.f + __expf(-ov));
      const float gcl = fminf(fmaxf(gv, -20.f), 20.f);
      const float e2g = __expf(2.f * gcl);
      const float gg = (e2g - 1.f) / (e2g + 1.f);
      creg = fg * creg + ig * gg;
      const float ccl = fminf(fmaxf(creg, -20.f), 20.f);
      const float e2c = __expf(2.f * ccl);
      const float th = (e2c - 1.f) / (e2c + 1.f);
      hn = og * th;
      const float hn2 = __shfl_xor(hn, 1);
      if ((tid & 1) == 0){
        unsigned pk = (unsigned)(unsigned short)f2bf(hn)
                    | ((unsigned)(unsigned short)f2bf(hn2) << 16);
        st_llc_u32(hWp + (size_t)cn * 1024 + cu, pk);
      }
    }
    asm volatile("s_waitcnt vmcnt(0)" ::: "memory");
    __syncthreads();                   // sync8: h stores at LLC
    if (tid == 0 && t < 63) st_llc_u32(&flagsB[(mh * 128 + jb) * 16], (unsigned)(t + 1));
    __builtin_nontemporal_store(hn, &out[((size_t)cn * 64 + t) * 1024 + cu]);
  }
}

// ---------------- launch ----------------

extern "C" void kernel_launch(void* const* d_in, const int* in_sizes, int n_in,
                              void* d_out, int out_size, void* d_ws, size_t ws_size,
                              hipStream_t stream)
{
  const float* x     = (const float*)d_in[0];
  const float* A     = (const float*)d_in[1];
  const float* Wx    = (const float*)d_in[2];
  const float* Wh    = (const float*)d_in[3];
  const float* Wattn = (const float*)d_in[4];
  const float* b     = (const float*)d_in[5];
  float* out = (float*)d_out;
  char* ws = (char*)d_ws;

  short*    W3T   = (short*)(ws + 0);             // 25165824
  short*    Abf   = (short*)(ws + 25165824);      //  4194304
  short*    Atr   = (short*)(ws + 29360128);      //  4194304
  short*    xbf   = (short*)(ws + 33554432);      // 16777216
  short*    xwx   = (short*)(ws + 50331648);      // 67108864
  short*    P     = (short*)(ws + 117440512);     // 16777216
  short*    hbuf  = (short*)(ws + 134217728);     // 17039360
  float*    wbuf  = (float*)(ws + 151257088);     //  1048576
  float*    cbuf  = (float*)(ws + 152305664);     //   524288
  unsigned* flags = (unsigned*)(ws + 152829952);  //    32768

  hipLaunchKernelGGL(k_wt,    dim3(48 * 64), dim3(256), 0, stream, Wx, Wh, Wattn, W3T);
  hipLaunchKernelGGL(k_cast,  dim3(2097152 / 256), dim3(256), 0, stream, x, xbf, 2097152);
  hipLaunchKernelGGL(k_castA, dim3(128), dim3(256), 0, stream, A, Abf, Atr);
  hipLaunchKernelGGL(k_init,  dim3(512), dim3(256), 0, stream, A, cbuf, hbuf, flags);
  hipLaunchKernelGGL(k_xwx,   dim3(2048), dim3(256), 0, stream, xbf, W3T, xwx);
  hipLaunchKernelGGL(k_pw,    dim3(2048), dim3(256), 0, stream, W3T, Atr, P);
  hipLaunchKernelGGL(k_loop,  dim3(256), dim3(512), 0, stream,
                     W3T, Abf, P, hbuf, wbuf, cbuf, xwx, b, out, flags);
}